// Round 5
// baseline (383.507 us; speedup 1.0000x reference)
//
#include <hip/hip_runtime.h>
#include <hip/hip_bf16.h>

#define SEQ   101
#define BATCH 16384
#define INP   9
#define HID   32
#define NOUT  3
#define HSlin 3232     // HID*SEQ

typedef __attribute__((ext_vector_type(8))) short short8;     // 8 bf16 (4 VGPRs)
typedef __attribute__((ext_vector_type(4))) float f32x4;      // MFMA C/D
typedef __attribute__((ext_vector_type(4))) unsigned u32x4;

#define LOG2E   1.4426950408889634f
#define N2LOG2E (-2.8853900817779268f)

__device__ __forceinline__ unsigned hi16_of(float f) {        // truncate to bf16
    return __float_as_uint(f) >> 16;
}
__device__ __forceinline__ unsigned lo16_of(float f) {        // residual as bf16
    unsigned u = __float_as_uint(f);
    float lo = f - __uint_as_float(u & 0xffff0000u);
    return __float_as_uint(lo) >> 16;
}
// one v_perm_b32: bf16-trunc of a -> bits[15:0], b -> bits[31:16]
__device__ __forceinline__ unsigned pack2(float a, float b) {
    return __builtin_amdgcn_perm(__float_as_uint(b), __float_as_uint(a), 0x07060302u);
}
__device__ __forceinline__ float losub(float f) {             // bf16 residual as float
    return f - __uint_as_float(__float_as_uint(f) & 0xffff0000u);
}

// Swapped-operand scheme: gates^T = W * [x|h]^T  (see R4 comments).
// NEW: all W/bias rows pre-scaled by log2e (i,f,o) / 2*log2e (g) so activations
// use raw v_exp_f32 (exp2) with no per-use multiply.
__global__ void prep_kernel(const float* __restrict__ W_ih, const float* __restrict__ W_hh,
                            const float* __restrict__ b_ih, const float* __restrict__ b_hh,
                            unsigned short* __restrict__ whh_hi, unsigned short* __restrict__ whh_lo,
                            unsigned short* __restrict__ wih, float* __restrict__ biasc) {
    int tid = threadIdx.x;            // 0..511 : t = tid>>6, l = tid&63
    int l   = tid & 63;
    int t   = tid >> 6;
    int row = l & 15;                 // gate-in-tile
    int g   = l >> 4;
    int gate = 16 * t + row;
    float sc = ((gate >> 5) == 2) ? (2.f * LOG2E) : LOG2E;    // g-gate: tanh needs e^{-2g}
    for (int j = 0; j < 8; ++j) {
        int u = 4 * g + (j & 3) + 16 * (j >> 2);     // pi(8g+j)
        float whh = W_hh[gate * HID + u] * sc;
        whh_hi[tid * 8 + j] = (unsigned short)hi16_of(whh);
        whh_lo[tid * 8 + j] = (unsigned short)lo16_of(whh);
        int k = 8 * g + j;
        const float* Wr = W_ih + gate * INP;
        unsigned v;
        if      (k < 8)   v = hi16_of(Wr[k] * sc);
        else if (k < 16)  v = lo16_of(Wr[k - 8] * sc);
        else if (k < 24)  v = hi16_of(Wr[k - 16] * sc);
        else if (k == 24) v = hi16_of(Wr[8] * sc);
        else if (k == 25) v = lo16_of(Wr[8] * sc);
        else if (k == 26) v = hi16_of(Wr[8] * sc);
        else              v = 0u;
        wih[tid * 8 + j] = (unsigned short)v;
    }
    if (tid < 4 * HID) {
        float bs = ((tid >> 5) == 2) ? (2.f * LOG2E) : LOG2E;
        biasc[tid] = (b_ih[tid] + b_hh[tid]) * bs;
    }
}

// 2-stage cross-lane reduce, then lanes 0..15 fire 3 non-returning atomics each
// to their exactly-computed output row. No low/high split, no edge cases.
__device__ __forceinline__ void reduce_emit(float p0, float p1, float p2,
                                            unsigned sb0, float* __restrict__ accp, int lane) {
    p0 += __shfl_xor(p0, 16); p1 += __shfl_xor(p1, 16); p2 += __shfl_xor(p2, 16);
    p0 += __shfl_xor(p0, 32); p1 += __shfl_xor(p1, 32); p2 += __shfl_xor(p2, 32);
    if (lane < 16) {          // lane c holds the sum for batch col c
        unsigned r = (sb0 + (unsigned)lane) / 101u;   // magic-mul div
        atomicAdd(&accp[r * 3 + 0], p0);
        atomicAdd(&accp[r * 3 + 1], p1);
        atomicAdd(&accp[r * 3 + 2], p2);
    }
}

// One wave per 16 batch rows; recurrence fully register-resident (no LDS).
__global__ __launch_bounds__(64, 1) void lstm_kernel(
    const float* __restrict__ x,                 // [SEQ][BATCH][INP]
    const unsigned short* __restrict__ whh_hi_g, // [8][64][8] A-frags
    const unsigned short* __restrict__ whh_lo_g,
    const unsigned short* __restrict__ wih_g,
    const float* __restrict__ biasc,             // [4H] (pre-scaled)
    const float* __restrict__ W_lin,             // [NOUT][HSlin]
    float* __restrict__ accp)                    // [BATCH][NOUT] accumulators
{
    const int lane = threadIdx.x;
    const int c    = lane & 15;        // batch col
    const int g    = lane >> 4;
    const int b0   = blockIdx.x * 16;
    const int b    = b0 + c;

    // Static A-fragments + per-lane bias quads (live across all steps)
    short8 whi[8], wlo[8], xw[8];
    f32x4 biasv[8];
#pragma unroll
    for (int t = 0; t < 8; ++t) {
        whi[t] = *reinterpret_cast<const short8*>(whh_hi_g + (t * 64 + lane) * 8);
        wlo[t] = *reinterpret_cast<const short8*>(whh_lo_g + (t * 64 + lane) * 8);
        xw[t]  = *reinterpret_cast<const short8*>(wih_g    + (t * 64 + lane) * 8);
        biasv[t] = *reinterpret_cast<const f32x4*>(biasc + 16 * t + 4 * g);
    }

    const bool g01 = (g < 2);
    const bool g2  = (g == 2);

    float cst[2][4] = {{0.f,0.f,0.f,0.f},{0.f,0.f,0.f,0.f}};
    float hlc[2][4] = {{0.f,0.f,0.f,0.f},{0.f,0.f,0.f,0.f}};  // h[half][q]: unit 16*half+4g+q, batch c
    float xv[9];
    {
        const float* xp = x + (size_t)b * INP;           // s = 0
#pragma unroll
        for (int i = 0; i < 9; ++i) xv[i] = xp[i];
    }

    float pp0 = 0.f, pp1 = 0.f, pp2 = 0.f;               // staged W_lin partials
    unsigned psb = 0;

    for (int s = 0; s < SEQ; ++s) {
        // (0) this step's W_lin weights (consumed after activations)
        unsigned blk  = (unsigned)s * BATCH + (unsigned)b;
        unsigned r    = blk / 101u;
        unsigned slot = blk - r * 101u;
        const float* wl = W_lin + slot * HID + 4 * g;
        float4 w0a = *(const float4*)(wl);
        float4 w0b = *(const float4*)(wl + 16);
        float4 w1a = *(const float4*)(wl + HSlin);
        float4 w1b = *(const float4*)(wl + HSlin + 16);
        float4 w2a = *(const float4*)(wl + 2 * HSlin);
        float4 w2b = *(const float4*)(wl + 2 * HSlin + 16);

        // (1) packed-x B fragment: v_perm packing + per-grp select
        short8 xa;
        {
            unsigned hp0 = pack2(xv[0], xv[1]), hp1 = pack2(xv[2], xv[3]);
            unsigned hp2 = pack2(xv[4], xv[5]), hp3 = pack2(xv[6], xv[7]);
            float l0 = losub(xv[0]), l1 = losub(xv[1]), l2 = losub(xv[2]), l3 = losub(xv[3]);
            float l4 = losub(xv[4]), l5 = losub(xv[5]), l6 = losub(xv[6]), l7 = losub(xv[7]);
            unsigned lp0 = pack2(l0, l1), lp1 = pack2(l2, l3);
            unsigned lp2 = pack2(l4, l5), lp3 = pack2(l6, l7);
            unsigned h8h8 = pack2(xv[8], xv[8]);
            unsigned l8w  = __float_as_uint(losub(xv[8])) >> 16;
            u32x4 xt;
            xt[0] = g01 ? hp0 : (g2 ? lp0 : h8h8);
            xt[1] = g01 ? hp1 : (g2 ? lp1 : l8w);
            xt[2] = g01 ? hp2 : (g2 ? lp2 : 0u);
            xt[3] = g01 ? hp3 : (g2 ? lp3 : 0u);
            xa = __builtin_bit_cast(short8, xt);
        }
        // (2) h B-fragment = own h, hi/lo via v_perm
        short8 bh, bl;
        {
            u32x4 ph, pl;
            ph[0] = pack2(hlc[0][0], hlc[0][1]); ph[1] = pack2(hlc[0][2], hlc[0][3]);
            ph[2] = pack2(hlc[1][0], hlc[1][1]); ph[3] = pack2(hlc[1][2], hlc[1][3]);
            pl[0] = pack2(losub(hlc[0][0]), losub(hlc[0][1]));
            pl[1] = pack2(losub(hlc[0][2]), losub(hlc[0][3]));
            pl[2] = pack2(losub(hlc[1][0]), losub(hlc[1][1]));
            pl[3] = pack2(losub(hlc[1][2]), losub(hlc[1][3]));
            bh = __builtin_bit_cast(short8, ph);
            bl = __builtin_bit_cast(short8, pl);
        }
        // (3) gates^T: 8 tiles x 4 MFMA (A = static weight frags)
        f32x4 acc[8];
#pragma unroll
        for (int t = 0; t < 8; ++t) {
            acc[t] = __builtin_amdgcn_mfma_f32_16x16x32_bf16(xw[t],  xa, biasv[t], 0, 0, 0);
            acc[t] = __builtin_amdgcn_mfma_f32_16x16x32_bf16(whi[t], bh, acc[t],   0, 0, 0);
            acc[t] = __builtin_amdgcn_mfma_f32_16x16x32_bf16(wlo[t], bh, acc[t],   0, 0, 0);
            acc[t] = __builtin_amdgcn_mfma_f32_16x16x32_bf16(whi[t], bl, acc[t],   0, 0, 0);
        }
        // (4) previous step's reduce + atomics — hides under MFMA latency
        if (s > 0) reduce_emit(pp0, pp1, pp2, psb, accp, lane);

        // (5) prefetch next step's x
        float xn[9];
        if (s < SEQ - 1) {
            const float* xpn = x + ((size_t)(s + 1) * BATCH + b) * INP;
#pragma unroll
            for (int i = 0; i < 9; ++i) xn[i] = xpn[i];
        }

        // (6) activations (gates pre-scaled: raw exp2, negate folded as modifier)
#pragma unroll
        for (int half = 0; half < 2; ++half) {
#pragma unroll
            for (int q = 0; q < 4; ++q) {
                float iv = acc[0 + half][q], fv = acc[2 + half][q];
                float gv = acc[4 + half][q], ov = acc[6 + half][q];
                float ef = __builtin_amdgcn_exp2f(-fv);
                float sf = __builtin_amdgcn_rcpf(1.f + ef);          // sigma(f)
                float ei = __builtin_amdgcn_exp2f(-iv);
                float eg = __builtin_amdgcn_exp2f(-gv);              // e^{-2g}
                float st = (1.f - eg) * __builtin_amdgcn_rcpf((1.f + ei) * (1.f + eg));
                float cn = fmaf(sf, cst[half][q], st);
                cst[half][q] = cn;
                float eo = __builtin_amdgcn_exp2f(-ov);
                float ec = __builtin_amdgcn_exp2f(cn * N2LOG2E);     // e^{-2c}
                hlc[half][q] = (1.f - ec) * __builtin_amdgcn_rcpf((1.f + eo) * (1.f + ec));
            }
        }
        if (s < SEQ - 1) {
#pragma unroll
            for (int i = 0; i < 9; ++i) xv[i] = xn[i];
        }

        // (7) this step's W_lin partials (units 4g+q <- half0, 16+4g+q <- half1)
        pp0 = w0a.x*hlc[0][0] + w0a.y*hlc[0][1] + w0a.z*hlc[0][2] + w0a.w*hlc[0][3]
            + w0b.x*hlc[1][0] + w0b.y*hlc[1][1] + w0b.z*hlc[1][2] + w0b.w*hlc[1][3];
        pp1 = w1a.x*hlc[0][0] + w1a.y*hlc[0][1] + w1a.z*hlc[0][2] + w1a.w*hlc[0][3]
            + w1b.x*hlc[1][0] + w1b.y*hlc[1][1] + w1b.z*hlc[1][2] + w1b.w*hlc[1][3];
        pp2 = w2a.x*hlc[0][0] + w2a.y*hlc[0][1] + w2a.z*hlc[0][2] + w2a.w*hlc[0][3]
            + w2b.x*hlc[1][0] + w2b.y*hlc[1][1] + w2b.z*hlc[1][2] + w2b.w*hlc[1][3];
        psb = (unsigned)s * BATCH + (unsigned)b0;
    }
    // epilogue: reduce for s = SEQ-1
    reduce_emit(pp0, pp1, pp2, psb, accp, lane);
}

__global__ void finalize_kernel(const float* __restrict__ acc, const float* __restrict__ b_lin,
                                float* __restrict__ out) {
    int i = blockIdx.x * blockDim.x + threadIdx.x;
    if (i < BATCH * NOUT) {
        int r = i / 3;
        int o = i - r * 3;
        out[i] = acc[i] + b_lin[o];
    }
}

extern "C" void kernel_launch(void* const* d_in, const int* in_sizes, int n_in,
                              void* d_out, int out_size, void* d_ws, size_t ws_size,
                              hipStream_t stream) {
    const float* x     = (const float*)d_in[0];
    const float* W_ih  = (const float*)d_in[1];
    const float* W_hh  = (const float*)d_in[2];
    const float* b_ih  = (const float*)d_in[3];
    const float* b_hh  = (const float*)d_in[4];
    const float* W_lin = (const float*)d_in[5];
    const float* b_lin = (const float*)d_in[6];
    float* out = (float*)d_out;

    // ws: acc[49160] f32 | whh_hi[4096] u16 | whh_lo[4096] u16 | wih[4096] u16 | biasc[128] f32
    float* accp = (float*)d_ws;
    unsigned short* whh_hi = (unsigned short*)(accp + 49160);
    unsigned short* whh_lo = whh_hi + 4096;
    unsigned short* wih    = whh_lo + 4096;
    float* biasc = (float*)(wih + 4096);

    hipMemsetAsync(accp, 0, 49160 * sizeof(float), stream);
    hipLaunchKernelGGL(prep_kernel, dim3(1), dim3(512), 0, stream,
                       W_ih, W_hh, b_ih, b_hh, whh_hi, whh_lo, wih, biasc);
    hipLaunchKernelGGL(lstm_kernel, dim3(BATCH / 16), dim3(64), 0, stream,
                       x, whh_hi, whh_lo, wih, biasc, W_lin, accp);
    hipLaunchKernelGGL(finalize_kernel, dim3((BATCH * NOUT + 255) / 256), dim3(256), 0, stream,
                       accp, b_lin, out);
}

// Round 6
// 174.139 us; speedup vs baseline: 2.2023x; 2.2023x over previous
//
#include <hip/hip_runtime.h>
#include <hip/hip_bf16.h>

#define SEQ   101
#define BATCH 16384
#define INP   9
#define HID   32
#define NOUT  3
#define HSlin 3232          // HID*SEQ
#define SB    (SEQ * BATCH) // 1,654,784 cols in flattened (s,b) space

typedef __attribute__((ext_vector_type(8))) short short8;     // 8 bf16 (4 VGPRs)
typedef __attribute__((ext_vector_type(4))) float f32x4;      // MFMA C/D
typedef __attribute__((ext_vector_type(4))) unsigned u32x4;

#define LOG2E   1.4426950408889634f
#define N2LOG2E (-2.8853900817779268f)

__device__ __forceinline__ unsigned hi16_of(float f) {        // truncate to bf16
    return __float_as_uint(f) >> 16;
}
__device__ __forceinline__ unsigned lo16_of(float f) {        // residual as bf16
    unsigned u = __float_as_uint(f);
    float lo = f - __uint_as_float(u & 0xffff0000u);
    return __float_as_uint(lo) >> 16;
}
// one v_perm_b32: bf16-trunc of a -> bits[15:0], b -> bits[31:16]
__device__ __forceinline__ unsigned pack2(float a, float b) {
    return __builtin_amdgcn_perm(__float_as_uint(b), __float_as_uint(a), 0x07060302u);
}
__device__ __forceinline__ float losub(float f) {             // bf16 residual as float
    return f - __uint_as_float(__float_as_uint(f) & 0xffff0000u);
}

// Swapped-operand scheme: gates^T = W * [x|h]^T  (verified R4/R5).
// Weights pre-scaled by log2e (i,f,o) / 2*log2e (g) so activations use raw exp2.
__global__ void prep_kernel(const float* __restrict__ W_ih, const float* __restrict__ W_hh,
                            const float* __restrict__ b_ih, const float* __restrict__ b_hh,
                            unsigned short* __restrict__ whh_hi, unsigned short* __restrict__ whh_lo,
                            unsigned short* __restrict__ wih, float* __restrict__ biasc) {
    int tid = threadIdx.x;            // 0..511 : t = tid>>6, l = tid&63
    int l   = tid & 63;
    int t   = tid >> 6;
    int row = l & 15;                 // gate-in-tile
    int g   = l >> 4;
    int gate = 16 * t + row;
    float sc = ((gate >> 5) == 2) ? (2.f * LOG2E) : LOG2E;    // g-gate: tanh needs e^{-2g}
    for (int j = 0; j < 8; ++j) {
        int u = 4 * g + (j & 3) + 16 * (j >> 2);     // pi(8g+j)
        float whh = W_hh[gate * HID + u] * sc;
        whh_hi[tid * 8 + j] = (unsigned short)hi16_of(whh);
        whh_lo[tid * 8 + j] = (unsigned short)lo16_of(whh);
        int k = 8 * g + j;
        const float* Wr = W_ih + gate * INP;
        unsigned v;
        if      (k < 8)   v = hi16_of(Wr[k] * sc);
        else if (k < 16)  v = lo16_of(Wr[k - 8] * sc);
        else if (k < 24)  v = hi16_of(Wr[k - 16] * sc);
        else if (k == 24) v = hi16_of(Wr[8] * sc);
        else if (k == 25) v = lo16_of(Wr[8] * sc);
        else if (k == 26) v = hi16_of(Wr[8] * sc);
        else              v = 0u;
        wih[tid * 8 + j] = (unsigned short)v;
    }
    if (tid < 4 * HID) {
        float bs = ((tid >> 5) == 2) ? (2.f * LOG2E) : LOG2E;
        biasc[tid] = (b_ih[tid] + b_hh[tid]) * bs;
    }
}

// Producer/consumer: block = 2 waves over 16 batch rows.
//   wave 0 (consumer): recurrence only — pack h, 32 MFMA, activations, h->LDS.
//   wave 1 (producer): x loads, xa packing (1 step ahead), W_lin partials for
//                      h(s-1), xor-reduce, plane stores (or atomic fallback).
// One barrier per step; xa ring + h buffer double-buffered in LDS.
template<bool PLANES>
__global__ __launch_bounds__(128, 2) void lstm_kernel(
    const float* __restrict__ x,                 // [SEQ][BATCH][INP]
    const unsigned short* __restrict__ whh_hi_g, // [8][64][8] A-frags
    const unsigned short* __restrict__ whh_lo_g,
    const unsigned short* __restrict__ wih_g,
    const float* __restrict__ biasc,             // [4H] (pre-scaled)
    const float* __restrict__ W_lin,             // [NOUT][HSlin]
    float* __restrict__ dataout)                 // planes [3][SB]  (or accp fallback)
{
    __shared__ unsigned xaring[2][4][64];        // xa fragments, 1 step ahead
    __shared__ float    hbuf[2][8][64];          // h handoff consumer->producer
    const int tid  = threadIdx.x;
    const int lane = tid & 63;
    const int w    = __builtin_amdgcn_readfirstlane(tid >> 6);  // 0=consumer 1=producer
    const int c    = lane & 15;        // batch col
    const int g    = lane >> 4;
    const int b0   = blockIdx.x * 16;
    const int b    = b0 + c;

    // ---- per-wave persistent state ----
    short8 whi[8], wlo[8], xw[8];
    f32x4 biasv[8];
    float cst[2][4] = {{0.f,0.f,0.f,0.f},{0.f,0.f,0.f,0.f}};
    float hlc[2][4] = {{0.f,0.f,0.f,0.f},{0.f,0.f,0.f,0.f}};
    float xcur[9], xnxt[9];
    const bool g01 = (g < 2), g2 = (g == 2);

    if (w == 0) {
        // consumer: static A-fragments + bias quads
#pragma unroll
        for (int t = 0; t < 8; ++t) {
            whi[t] = *reinterpret_cast<const short8*>(whh_hi_g + (t * 64 + lane) * 8);
            wlo[t] = *reinterpret_cast<const short8*>(whh_lo_g + (t * 64 + lane) * 8);
            xw[t]  = *reinterpret_cast<const short8*>(wih_g    + (t * 64 + lane) * 8);
            biasv[t] = *reinterpret_cast<const f32x4*>(biasc + 16 * t + 4 * g);
        }
    } else {
        // producer prologue: xa(0) into ring slot 0, x(1) into xcur
        const float* xp = x + (size_t)b * INP;
#pragma unroll
        for (int i = 0; i < 9; ++i) xcur[i] = xp[i];
        unsigned hp0 = pack2(xcur[0], xcur[1]), hp1 = pack2(xcur[2], xcur[3]);
        unsigned hp2 = pack2(xcur[4], xcur[5]), hp3 = pack2(xcur[6], xcur[7]);
        unsigned lp0 = pack2(losub(xcur[0]), losub(xcur[1])), lp1 = pack2(losub(xcur[2]), losub(xcur[3]));
        unsigned lp2 = pack2(losub(xcur[4]), losub(xcur[5])), lp3 = pack2(losub(xcur[6]), losub(xcur[7]));
        unsigned h8h8 = pack2(xcur[8], xcur[8]);
        unsigned l8w  = __float_as_uint(losub(xcur[8])) >> 16;
        xaring[0][0][lane] = g01 ? hp0 : (g2 ? lp0 : h8h8);
        xaring[0][1][lane] = g01 ? hp1 : (g2 ? lp1 : l8w);
        xaring[0][2][lane] = g01 ? hp2 : (g2 ? lp2 : 0u);
        xaring[0][3][lane] = g01 ? hp3 : (g2 ? lp3 : 0u);
        const float* xp1 = x + ((size_t)BATCH + b) * INP;
#pragma unroll
        for (int i = 0; i < 9; ++i) xcur[i] = xp1[i];
    }

#pragma unroll 1
    for (int s = 0; s <= SEQ; ++s) {
        __syncthreads();   // xa(s) + h(s-1) visible

        if (w == 0) {
            if (s < SEQ) {
                // issue xa read early (consumed by the last MFMA of each tile)
                u32x4 xt;
#pragma unroll
                for (int j = 0; j < 4; ++j) xt[j] = xaring[s & 1][j][lane];
                short8 xa = __builtin_bit_cast(short8, xt);
                // pack bh/bl from own hlc (zero cross-lane movement)
                u32x4 ph, pl;
                ph[0] = pack2(hlc[0][0], hlc[0][1]); ph[1] = pack2(hlc[0][2], hlc[0][3]);
                ph[2] = pack2(hlc[1][0], hlc[1][1]); ph[3] = pack2(hlc[1][2], hlc[1][3]);
                pl[0] = pack2(losub(hlc[0][0]), losub(hlc[0][1]));
                pl[1] = pack2(losub(hlc[0][2]), losub(hlc[0][3]));
                pl[2] = pack2(losub(hlc[1][0]), losub(hlc[1][1]));
                pl[3] = pack2(losub(hlc[1][2]), losub(hlc[1][3]));
                short8 bh = __builtin_bit_cast(short8, ph);
                short8 bl = __builtin_bit_cast(short8, pl);
                // gates^T: 8 tiles x 4 MFMA; xa-MFMA last (hides the ds_read)
                f32x4 acc[8];
#pragma unroll
                for (int t = 0; t < 8; ++t) {
                    acc[t] = __builtin_amdgcn_mfma_f32_16x16x32_bf16(whi[t], bh, biasv[t], 0, 0, 0);
                    acc[t] = __builtin_amdgcn_mfma_f32_16x16x32_bf16(wlo[t], bh, acc[t],   0, 0, 0);
                    acc[t] = __builtin_amdgcn_mfma_f32_16x16x32_bf16(whi[t], bl, acc[t],   0, 0, 0);
                    acc[t] = __builtin_amdgcn_mfma_f32_16x16x32_bf16(xw[t],  xa, acc[t],   0, 0, 0);
                }
                // activations (pre-scaled gates: raw exp2)
#pragma unroll
                for (int half = 0; half < 2; ++half) {
#pragma unroll
                    for (int q = 0; q < 4; ++q) {
                        float iv = acc[0 + half][q], fv = acc[2 + half][q];
                        float gv = acc[4 + half][q], ov = acc[6 + half][q];
                        float ef = __builtin_amdgcn_exp2f(-fv);
                        float sf = __builtin_amdgcn_rcpf(1.f + ef);
                        float ei = __builtin_amdgcn_exp2f(-iv);
                        float eg = __builtin_amdgcn_exp2f(-gv);              // e^{-2g}
                        float st = (1.f - eg) * __builtin_amdgcn_rcpf((1.f + ei) * (1.f + eg));
                        float cn = fmaf(sf, cst[half][q], st);
                        cst[half][q] = cn;
                        float eo = __builtin_amdgcn_exp2f(-ov);
                        float ec = __builtin_amdgcn_exp2f(cn * N2LOG2E);     // e^{-2c}
                        hlc[half][q] = (1.f - ec) * __builtin_amdgcn_rcpf((1.f + eo) * (1.f + ec));
                        hbuf[s & 1][half * 4 + q][lane] = hlc[half][q];
                    }
                }
            }
        } else {
            // ---- producer ----
            if (s + 2 < SEQ) {                       // x(s+2) -> xnxt
                const float* xp = x + ((size_t)(s + 2) * BATCH + b) * INP;
#pragma unroll
                for (int i = 0; i < 9; ++i) xnxt[i] = xp[i];
            }
            // W_lin weights for step s-1 (issued early, consumed late)
            float4 w0a, w0b, w1a, w1b, w2a, w2b;
            if (s >= 1) {
                unsigned blk  = (unsigned)(s - 1) * BATCH + (unsigned)b;
                unsigned r    = blk / 101u;
                unsigned slot = blk - r * 101u;
                const float* wl = W_lin + slot * HID + 4 * g;
                w0a = *(const float4*)(wl);
                w0b = *(const float4*)(wl + 16);
                w1a = *(const float4*)(wl + HSlin);
                w1b = *(const float4*)(wl + HSlin + 16);
                w2a = *(const float4*)(wl + 2 * HSlin);
                w2b = *(const float4*)(wl + 2 * HSlin + 16);
            }
            // pack xa(s+1) from xcur = x(s+1)
            if (s + 1 < SEQ) {
                unsigned hp0 = pack2(xcur[0], xcur[1]), hp1 = pack2(xcur[2], xcur[3]);
                unsigned hp2 = pack2(xcur[4], xcur[5]), hp3 = pack2(xcur[6], xcur[7]);
                unsigned lp0 = pack2(losub(xcur[0]), losub(xcur[1])), lp1 = pack2(losub(xcur[2]), losub(xcur[3]));
                unsigned lp2 = pack2(losub(xcur[4]), losub(xcur[5])), lp3 = pack2(losub(xcur[6]), losub(xcur[7]));
                unsigned h8h8 = pack2(xcur[8], xcur[8]);
                unsigned l8w  = __float_as_uint(losub(xcur[8])) >> 16;
                int slot2 = (s + 1) & 1;
                xaring[slot2][0][lane] = g01 ? hp0 : (g2 ? lp0 : h8h8);
                xaring[slot2][1][lane] = g01 ? hp1 : (g2 ? lp1 : l8w);
                xaring[slot2][2][lane] = g01 ? hp2 : (g2 ? lp2 : 0u);
                xaring[slot2][3][lane] = g01 ? hp3 : (g2 ? lp3 : 0u);
            }
            // W_lin partials for h(s-1)
            if (s >= 1) {
                float hn[8];
#pragma unroll
                for (int j = 0; j < 8; ++j) hn[j] = hbuf[(s - 1) & 1][j][lane];
                float p0 = w0a.x*hn[0] + w0a.y*hn[1] + w0a.z*hn[2] + w0a.w*hn[3]
                         + w0b.x*hn[4] + w0b.y*hn[5] + w0b.z*hn[6] + w0b.w*hn[7];
                float p1 = w1a.x*hn[0] + w1a.y*hn[1] + w1a.z*hn[2] + w1a.w*hn[3]
                         + w1b.x*hn[4] + w1b.y*hn[5] + w1b.z*hn[6] + w1b.w*hn[7];
                float p2 = w2a.x*hn[0] + w2a.y*hn[1] + w2a.z*hn[2] + w2a.w*hn[3]
                         + w2b.x*hn[4] + w2b.y*hn[5] + w2b.z*hn[6] + w2b.w*hn[7];
                // sum the 4 g-groups -> lanes 0..15 hold per-col sums
                p0 += __shfl_xor(p0, 16); p1 += __shfl_xor(p1, 16); p2 += __shfl_xor(p2, 16);
                p0 += __shfl_xor(p0, 32); p1 += __shfl_xor(p1, 32); p2 += __shfl_xor(p2, 32);
                if (PLANES) {
                    if (lane < 16) {
                        unsigned blk = (unsigned)(s - 1) * BATCH + (unsigned)(b0 + lane);
                        dataout[0 * SB + blk] = p0;
                        dataout[1 * SB + blk] = p1;
                        dataout[2 * SB + blk] = p2;
                    }
                } else {
                    // fallback: split by output row, butterfly, lane-0 atomics
                    unsigned blk  = (unsigned)(s - 1) * BATCH + (unsigned)b;
                    unsigned r    = blk / 101u;
                    unsigned rmin = ((unsigned)(s - 1) * BATCH + (unsigned)b0) / 101u;
                    bool low = (r == rmin);
                    float a0 = low ? p0 : 0.f, a1 = low ? p1 : 0.f, a2 = low ? p2 : 0.f;
                    float d0 = low ? 0.f : p0, d1 = low ? 0.f : p1, d2 = low ? 0.f : p2;
#pragma unroll
                    for (int m = 1; m < 16; m <<= 1) {
                        a0 += __shfl_xor(a0, m); a1 += __shfl_xor(a1, m); a2 += __shfl_xor(a2, m);
                        d0 += __shfl_xor(d0, m); d1 += __shfl_xor(d1, m); d2 += __shfl_xor(d2, m);
                    }
                    int anyhi = __any(!low);
                    if (lane == 0) {
                        atomicAdd(&dataout[rmin * 3 + 0], a0);
                        atomicAdd(&dataout[rmin * 3 + 1], a1);
                        atomicAdd(&dataout[rmin * 3 + 2], a2);
                        if (anyhi) {
                            atomicAdd(&dataout[(rmin + 1u) * 3 + 0], d0);
                            atomicAdd(&dataout[(rmin + 1u) * 3 + 1], d1);
                            atomicAdd(&dataout[(rmin + 1u) * 3 + 2], d2);
                        }
                    }
                }
            }
            if (s + 2 < SEQ) {
#pragma unroll
                for (int i = 0; i < 9; ++i) xcur[i] = xnxt[i];
            }
        }
    }
}

// Plane path: one wave per output row sums its 101 contiguous cols.
__global__ void finalize_planes(const float* __restrict__ planes, const float* __restrict__ b_lin,
                                float* __restrict__ out) {
    int wid = (blockIdx.x * blockDim.x + threadIdx.x) >> 6;   // row 0..16383
    int l   = threadIdx.x & 63;
    float v[3];
#pragma unroll
    for (int o = 0; o < 3; ++o) {
        const float* p = planes + (size_t)o * SB + (size_t)wid * 101;
        float t = p[l] + ((l < 37) ? p[l + 64] : 0.f);
#pragma unroll
        for (int m = 1; m < 64; m <<= 1) t += __shfl_xor(t, m);
        v[o] = t;
    }
    if (l == 0) {
        out[wid * 3 + 0] = v[0] + b_lin[0];
        out[wid * 3 + 1] = v[1] + b_lin[1];
        out[wid * 3 + 2] = v[2] + b_lin[2];
    }
}

__global__ void finalize_acc(const float* __restrict__ acc, const float* __restrict__ b_lin,
                             float* __restrict__ out) {
    int i = blockIdx.x * blockDim.x + threadIdx.x;
    if (i < BATCH * NOUT) {
        int r = i / 3;
        int o = i - r * 3;
        out[i] = acc[i] + b_lin[o];
    }
}

extern "C" void kernel_launch(void* const* d_in, const int* in_sizes, int n_in,
                              void* d_out, int out_size, void* d_ws, size_t ws_size,
                              hipStream_t stream) {
    const float* x     = (const float*)d_in[0];
    const float* W_ih  = (const float*)d_in[1];
    const float* W_hh  = (const float*)d_in[2];
    const float* b_ih  = (const float*)d_in[3];
    const float* b_hh  = (const float*)d_in[4];
    const float* W_lin = (const float*)d_in[5];
    const float* b_lin = (const float*)d_in[6];
    float* out = (float*)d_out;

    // ws: whh_hi[4096]u16 | whh_lo[4096]u16 | wih[4096]u16 | biasc[128]f32 | data...
    unsigned short* whh_hi = (unsigned short*)d_ws;
    unsigned short* whh_lo = whh_hi + 4096;
    unsigned short* wih    = whh_lo + 4096;
    float* biasc = (float*)(wih + 4096);
    float* data  = (float*)((char*)d_ws + 25600);

    size_t need_planes = 25600 + (size_t)3 * SB * sizeof(float);
    bool planes = ws_size >= need_planes;

    hipLaunchKernelGGL(prep_kernel, dim3(1), dim3(512), 0, stream,
                       W_ih, W_hh, b_ih, b_hh, whh_hi, whh_lo, wih, biasc);
    if (planes) {
        hipLaunchKernelGGL((lstm_kernel<true>), dim3(BATCH / 16), dim3(128), 0, stream,
                           x, whh_hi, whh_lo, wih, biasc, W_lin, data);
        hipLaunchKernelGGL(finalize_planes, dim3(BATCH / 4), dim3(256), 0, stream,
                           data, b_lin, out);
    } else {
        hipMemsetAsync(data, 0, 49160 * sizeof(float), stream);
        hipLaunchKernelGGL((lstm_kernel<false>), dim3(BATCH / 16), dim3(128), 0, stream,
                           x, whh_hi, whh_lo, wih, biasc, W_lin, data);
        hipLaunchKernelGGL(finalize_acc, dim3((BATCH * NOUT + 255) / 256), dim3(256), 0, stream,
                           data, b_lin, out);
    }
}

// Round 7
// 162.792 us; speedup vs baseline: 2.3558x; 1.0697x over previous
//
#include <hip/hip_runtime.h>
#include <hip/hip_bf16.h>

#define SEQ   101
#define BATCH 16384
#define INP   9
#define HID   32
#define NOUT  3
#define HSlin 3232          // HID*SEQ
#define SB    (SEQ * BATCH) // flattened (s,b) cols

typedef __attribute__((ext_vector_type(8))) short short8;     // 8 bf16 (4 VGPRs)
typedef __attribute__((ext_vector_type(4))) float f32x4;      // MFMA C/D
typedef __attribute__((ext_vector_type(4))) unsigned u32x4;

#define LOG2E   1.4426950408889634f
#define N2LOG2E (-2.8853900817779268f)

// Raw barrier: drain LDS ops only — VMEM (x prefetch, plane stores) stays in
// flight across steps. Cross-wave traffic is LDS-only, so lgkmcnt(0) suffices.
#define BARSYNC() asm volatile("s_waitcnt lgkmcnt(0)\n\ts_barrier" ::: "memory")

__device__ __forceinline__ unsigned hi16_of(float f) {        // truncate to bf16
    return __float_as_uint(f) >> 16;
}
__device__ __forceinline__ unsigned lo16_of(float f) {        // residual as bf16
    unsigned u = __float_as_uint(f);
    float lo = f - __uint_as_float(u & 0xffff0000u);
    return __float_as_uint(lo) >> 16;
}
// one v_perm_b32: bf16-trunc of a -> bits[15:0], b -> bits[31:16]
__device__ __forceinline__ unsigned pack2(float a, float b) {
    return __builtin_amdgcn_perm(__float_as_uint(b), __float_as_uint(a), 0x07060302u);
}
__device__ __forceinline__ float losub(float f) {             // bf16 residual as float
    return f - __uint_as_float(__float_as_uint(f) & 0xffff0000u);
}

// Swapped-operand scheme: gates^T = W * [x|h]^T  (verified R4-R6).
// Weights pre-scaled by log2e (i,f,o) / 2*log2e (g) so activations use raw exp2.
__global__ void prep_kernel(const float* __restrict__ W_ih, const float* __restrict__ W_hh,
                            const float* __restrict__ b_ih, const float* __restrict__ b_hh,
                            unsigned short* __restrict__ whh_hi, unsigned short* __restrict__ whh_lo,
                            unsigned short* __restrict__ wih, float* __restrict__ biasc) {
    int tid = threadIdx.x;            // 0..511 : t = tid>>6, l = tid&63
    int l   = tid & 63;
    int t   = tid >> 6;
    int row = l & 15;                 // gate-in-tile
    int g   = l >> 4;
    int gate = 16 * t + row;
    float sc = ((gate >> 5) == 2) ? (2.f * LOG2E) : LOG2E;    // g-gate: tanh needs e^{-2g}
    for (int j = 0; j < 8; ++j) {
        int u = 4 * g + (j & 3) + 16 * (j >> 2);     // pi(8g+j)
        float whh = W_hh[gate * HID + u] * sc;
        whh_hi[tid * 8 + j] = (unsigned short)hi16_of(whh);
        whh_lo[tid * 8 + j] = (unsigned short)lo16_of(whh);
        int k = 8 * g + j;
        const float* Wr = W_ih + gate * INP;
        unsigned v;
        if      (k < 8)   v = hi16_of(Wr[k] * sc);
        else if (k < 16)  v = lo16_of(Wr[k - 8] * sc);
        else if (k < 24)  v = hi16_of(Wr[k - 16] * sc);
        else if (k == 24) v = hi16_of(Wr[8] * sc);
        else if (k == 25) v = lo16_of(Wr[8] * sc);
        else if (k == 26) v = hi16_of(Wr[8] * sc);
        else              v = 0u;
        wih[tid * 8 + j] = (unsigned short)v;
    }
    if (tid < 4 * HID) {
        float bs = ((tid >> 5) == 2) ? (2.f * LOG2E) : LOG2E;
        biasc[tid] = (b_ih[tid] + b_hh[tid]) * bs;
    }
}

// Producer/consumer, 2 waves/block over 16 batch rows, 1 raw barrier per step.
//   wave 0 (consumer): pack h, 32 MFMA (setprio-wrapped), activations, h->LDS.
//   wave 1 (producer): x loads (2 ahead, never drained), xa packing (1 ahead),
//                      W_lin loads, partial dots for h(s-1), reduce, plane stores.
template<bool PLANES>
__global__ __launch_bounds__(128, 2) void lstm_kernel(
    const float* __restrict__ x,                 // [SEQ][BATCH][INP]
    const unsigned short* __restrict__ whh_hi_g, // [8][64][8] A-frags
    const unsigned short* __restrict__ whh_lo_g,
    const unsigned short* __restrict__ wih_g,
    const float* __restrict__ biasc,             // [4H] (pre-scaled)
    const float* __restrict__ W_lin,             // [NOUT][HSlin]
    float* __restrict__ dataout)                 // planes [3][SB]  (or accp fallback)
{
    __shared__ unsigned xaring[2][4][64];        // xa fragments, 1 step ahead
    __shared__ float    hbuf[2][8][64];          // h handoff consumer->producer
    const int tid  = threadIdx.x;
    const int lane = tid & 63;
    const int w    = __builtin_amdgcn_readfirstlane(tid >> 6);  // 0=consumer 1=producer
    const int c    = lane & 15;        // batch col
    const int g    = lane >> 4;
    const int b0   = blockIdx.x * 16;
    const int b    = b0 + c;

    short8 whi[8], wlo[8], xw[8];
    f32x4 biasv[8];
    float cst[2][4] = {{0.f,0.f,0.f,0.f},{0.f,0.f,0.f,0.f}};
    float hlc[2][4] = {{0.f,0.f,0.f,0.f},{0.f,0.f,0.f,0.f}};
    float xcur[9], xnxt[9];
    const bool g01 = (g < 2), g2 = (g == 2);

    if (w == 0) {
        // consumer: static A-fragments + bias quads
#pragma unroll
        for (int t = 0; t < 8; ++t) {
            whi[t] = *reinterpret_cast<const short8*>(whh_hi_g + (t * 64 + lane) * 8);
            wlo[t] = *reinterpret_cast<const short8*>(whh_lo_g + (t * 64 + lane) * 8);
            xw[t]  = *reinterpret_cast<const short8*>(wih_g    + (t * 64 + lane) * 8);
            biasv[t] = *reinterpret_cast<const f32x4*>(biasc + 16 * t + 4 * g);
        }
    } else {
        // producer prologue: xa(0) into ring slot 0, x(1) into xcur
        const float* xp = x + (size_t)b * INP;
#pragma unroll
        for (int i = 0; i < 9; ++i) xcur[i] = xp[i];
        unsigned hp0 = pack2(xcur[0], xcur[1]), hp1 = pack2(xcur[2], xcur[3]);
        unsigned hp2 = pack2(xcur[4], xcur[5]), hp3 = pack2(xcur[6], xcur[7]);
        unsigned lp0 = pack2(losub(xcur[0]), losub(xcur[1])), lp1 = pack2(losub(xcur[2]), losub(xcur[3]));
        unsigned lp2 = pack2(losub(xcur[4]), losub(xcur[5])), lp3 = pack2(losub(xcur[6]), losub(xcur[7]));
        unsigned h8h8 = pack2(xcur[8], xcur[8]);
        unsigned l8w  = __float_as_uint(losub(xcur[8])) >> 16;
        xaring[0][0][lane] = g01 ? hp0 : (g2 ? lp0 : h8h8);
        xaring[0][1][lane] = g01 ? hp1 : (g2 ? lp1 : l8w);
        xaring[0][2][lane] = g01 ? hp2 : (g2 ? lp2 : 0u);
        xaring[0][3][lane] = g01 ? hp3 : (g2 ? lp3 : 0u);
        const float* xp1 = x + ((size_t)BATCH + b) * INP;
#pragma unroll
        for (int i = 0; i < 9; ++i) xcur[i] = xp1[i];
    }

#pragma unroll 1
    for (int s = 0; s <= SEQ; ++s) {
        BARSYNC();   // xa(s) + h(s-1) visible; VMEM stays in flight

        if (w == 0) {
            if (s < SEQ) {
                // xa read first (ds latency hides under the pack + bh-MFMAs)
                u32x4 xt;
#pragma unroll
                for (int j = 0; j < 4; ++j) xt[j] = xaring[s & 1][j][lane];
                short8 xa = __builtin_bit_cast(short8, xt);
                // pack bh/bl from own hlc (zero cross-lane movement)
                u32x4 ph, pl;
                ph[0] = pack2(hlc[0][0], hlc[0][1]); ph[1] = pack2(hlc[0][2], hlc[0][3]);
                ph[2] = pack2(hlc[1][0], hlc[1][1]); ph[3] = pack2(hlc[1][2], hlc[1][3]);
                pl[0] = pack2(losub(hlc[0][0]), losub(hlc[0][1]));
                pl[1] = pack2(losub(hlc[0][2]), losub(hlc[0][3]));
                pl[2] = pack2(losub(hlc[1][0]), losub(hlc[1][1]));
                pl[3] = pack2(losub(hlc[1][2]), losub(hlc[1][3]));
                short8 bh = __builtin_bit_cast(short8, ph);
                short8 bl = __builtin_bit_cast(short8, pl);
                // gates^T: 8 tiles x 4 MFMA; xa-MFMA last
                f32x4 acc[8];
                __builtin_amdgcn_s_setprio(1);
#pragma unroll
                for (int t = 0; t < 8; ++t) {
                    acc[t] = __builtin_amdgcn_mfma_f32_16x16x32_bf16(whi[t], bh, biasv[t], 0, 0, 0);
                    acc[t] = __builtin_amdgcn_mfma_f32_16x16x32_bf16(wlo[t], bh, acc[t],   0, 0, 0);
                    acc[t] = __builtin_amdgcn_mfma_f32_16x16x32_bf16(whi[t], bl, acc[t],   0, 0, 0);
                    acc[t] = __builtin_amdgcn_mfma_f32_16x16x32_bf16(xw[t],  xa, acc[t],   0, 0, 0);
                }
                __builtin_amdgcn_s_setprio(0);
                // activations (pre-scaled gates: raw exp2)
#pragma unroll
                for (int half = 0; half < 2; ++half) {
#pragma unroll
                    for (int q = 0; q < 4; ++q) {
                        float iv = acc[0 + half][q], fv = acc[2 + half][q];
                        float gv = acc[4 + half][q], ov = acc[6 + half][q];
                        float ef = __builtin_amdgcn_exp2f(-fv);
                        float sf = __builtin_amdgcn_rcpf(1.f + ef);
                        float ei = __builtin_amdgcn_exp2f(-iv);
                        float eg = __builtin_amdgcn_exp2f(-gv);              // e^{-2g}
                        float st = (1.f - eg) * __builtin_amdgcn_rcpf((1.f + ei) * (1.f + eg));
                        float cn = fmaf(sf, cst[half][q], st);
                        cst[half][q] = cn;
                        float eo = __builtin_amdgcn_exp2f(-ov);
                        float ec = __builtin_amdgcn_exp2f(cn * N2LOG2E);     // e^{-2c}
                        hlc[half][q] = (1.f - ec) * __builtin_amdgcn_rcpf((1.f + eo) * (1.f + ec));
                        hbuf[s & 1][half * 4 + q][lane] = hlc[half][q];
                    }
                }
            }
        } else {
            // ---- producer (all VMEM lives here; never drained at barriers) ----
            // W_lin weights for step s-1: issue first
            float4 w0a, w0b, w1a, w1b, w2a, w2b;
            if (s >= 1) {
                unsigned blk  = (unsigned)(s - 1) * BATCH + (unsigned)b;
                unsigned r    = blk / 101u;
                unsigned slot = blk - r * 101u;
                const float* wl = W_lin + slot * HID + 4 * g;
                w0a = *(const float4*)(wl);
                w0b = *(const float4*)(wl + 16);
                w1a = *(const float4*)(wl + HSlin);
                w1b = *(const float4*)(wl + HSlin + 16);
                w2a = *(const float4*)(wl + 2 * HSlin);
                w2b = *(const float4*)(wl + 2 * HSlin + 16);
            }
            if (s + 2 < SEQ) {                       // x(s+2) -> xnxt (2-deep prefetch)
                const float* xp = x + ((size_t)(s + 2) * BATCH + b) * INP;
#pragma unroll
                for (int i = 0; i < 9; ++i) xnxt[i] = xp[i];
            }
            // pack xa(s+1) from xcur = x(s+1)
            if (s + 1 < SEQ) {
                unsigned hp0 = pack2(xcur[0], xcur[1]), hp1 = pack2(xcur[2], xcur[3]);
                unsigned hp2 = pack2(xcur[4], xcur[5]), hp3 = pack2(xcur[6], xcur[7]);
                unsigned lp0 = pack2(losub(xcur[0]), losub(xcur[1])), lp1 = pack2(losub(xcur[2]), losub(xcur[3]));
                unsigned lp2 = pack2(losub(xcur[4]), losub(xcur[5])), lp3 = pack2(losub(xcur[6]), losub(xcur[7]));
                unsigned h8h8 = pack2(xcur[8], xcur[8]);
                unsigned l8w  = __float_as_uint(losub(xcur[8])) >> 16;
                int slot2 = (s + 1) & 1;
                xaring[slot2][0][lane] = g01 ? hp0 : (g2 ? lp0 : h8h8);
                xaring[slot2][1][lane] = g01 ? hp1 : (g2 ? lp1 : l8w);
                xaring[slot2][2][lane] = g01 ? hp2 : (g2 ? lp2 : 0u);
                xaring[slot2][3][lane] = g01 ? hp3 : (g2 ? lp3 : 0u);
            }
            // W_lin partials for h(s-1)
            if (s >= 1) {
                float hn[8];
#pragma unroll
                for (int j = 0; j < 8; ++j) hn[j] = hbuf[(s - 1) & 1][j][lane];
                float p0 = w0a.x*hn[0] + w0a.y*hn[1] + w0a.z*hn[2] + w0a.w*hn[3]
                         + w0b.x*hn[4] + w0b.y*hn[5] + w0b.z*hn[6] + w0b.w*hn[7];
                float p1 = w1a.x*hn[0] + w1a.y*hn[1] + w1a.z*hn[2] + w1a.w*hn[3]
                         + w1b.x*hn[4] + w1b.y*hn[5] + w1b.z*hn[6] + w1b.w*hn[7];
                float p2 = w2a.x*hn[0] + w2a.y*hn[1] + w2a.z*hn[2] + w2a.w*hn[3]
                         + w2b.x*hn[4] + w2b.y*hn[5] + w2b.z*hn[6] + w2b.w*hn[7];
                p0 += __shfl_xor(p0, 16); p1 += __shfl_xor(p1, 16); p2 += __shfl_xor(p2, 16);
                p0 += __shfl_xor(p0, 32); p1 += __shfl_xor(p1, 32); p2 += __shfl_xor(p2, 32);
                if (PLANES) {
                    if (lane < 16) {
                        unsigned blk = (unsigned)(s - 1) * BATCH + (unsigned)(b0 + lane);
                        dataout[0 * SB + blk] = p0;
                        dataout[1 * SB + blk] = p1;
                        dataout[2 * SB + blk] = p2;
                    }
                } else {
                    unsigned blk  = (unsigned)(s - 1) * BATCH + (unsigned)b;
                    unsigned r    = blk / 101u;
                    unsigned rmin = ((unsigned)(s - 1) * BATCH + (unsigned)b0) / 101u;
                    bool low = (r == rmin);
                    float a0 = low ? p0 : 0.f, a1 = low ? p1 : 0.f, a2 = low ? p2 : 0.f;
                    float d0 = low ? 0.f : p0, d1 = low ? 0.f : p1, d2 = low ? 0.f : p2;
#pragma unroll
                    for (int m = 1; m < 16; m <<= 1) {
                        a0 += __shfl_xor(a0, m); a1 += __shfl_xor(a1, m); a2 += __shfl_xor(a2, m);
                        d0 += __shfl_xor(d0, m); d1 += __shfl_xor(d1, m); d2 += __shfl_xor(d2, m);
                    }
                    int anyhi = __any(!low);
                    if (lane == 0) {
                        atomicAdd(&dataout[rmin * 3 + 0], a0);
                        atomicAdd(&dataout[rmin * 3 + 1], a1);
                        atomicAdd(&dataout[rmin * 3 + 2], a2);
                        if (anyhi) {
                            atomicAdd(&dataout[(rmin + 1u) * 3 + 0], d0);
                            atomicAdd(&dataout[(rmin + 1u) * 3 + 1], d1);
                            atomicAdd(&dataout[(rmin + 1u) * 3 + 2], d2);
                        }
                    }
                }
            }
            if (s + 2 < SEQ) {
#pragma unroll
                for (int i = 0; i < 9; ++i) xcur[i] = xnxt[i];
            }
        }
    }
}

// Plane path: one wave per output row sums its 101 contiguous cols.
__global__ void finalize_planes(const float* __restrict__ planes, const float* __restrict__ b_lin,
                                float* __restrict__ out) {
    int wid = (blockIdx.x * blockDim.x + threadIdx.x) >> 6;   // row 0..16383
    int l   = threadIdx.x & 63;
    float v[3];
#pragma unroll
    for (int o = 0; o < 3; ++o) {
        const float* p = planes + (size_t)o * SB + (size_t)wid * 101;
        float t = p[l] + ((l < 37) ? p[l + 64] : 0.f);
#pragma unroll
        for (int m = 1; m < 64; m <<= 1) t += __shfl_xor(t, m);
        v[o] = t;
    }
    if (l == 0) {
        out[wid * 3 + 0] = v[0] + b_lin[0];
        out[wid * 3 + 1] = v[1] + b_lin[1];
        out[wid * 3 + 2] = v[2] + b_lin[2];
    }
}

__global__ void finalize_acc(const float* __restrict__ acc, const float* __restrict__ b_lin,
                             float* __restrict__ out) {
    int i = blockIdx.x * blockDim.x + threadIdx.x;
    if (i < BATCH * NOUT) {
        int r = i / 3;
        int o = i - r * 3;
        out[i] = acc[i] + b_lin[o];
    }
}

extern "C" void kernel_launch(void* const* d_in, const int* in_sizes, int n_in,
                              void* d_out, int out_size, void* d_ws, size_t ws_size,
                              hipStream_t stream) {
    const float* x     = (const float*)d_in[0];
    const float* W_ih  = (const float*)d_in[1];
    const float* W_hh  = (const float*)d_in[2];
    const float* b_ih  = (const float*)d_in[3];
    const float* b_hh  = (const float*)d_in[4];
    const float* W_lin = (const float*)d_in[5];
    const float* b_lin = (const float*)d_in[6];
    float* out = (float*)d_out;

    // ws: whh_hi[4096]u16 | whh_lo[4096]u16 | wih[4096]u16 | biasc[128]f32 | data...
    unsigned short* whh_hi = (unsigned short*)d_ws;
    unsigned short* whh_lo = whh_hi + 4096;
    unsigned short* wih    = whh_lo + 4096;
    float* biasc = (float*)(wih + 4096);
    float* data  = (float*)((char*)d_ws + 25600);

    size_t need_planes = 25600 + (size_t)3 * SB * sizeof(float);
    bool planes = ws_size >= need_planes;

    hipLaunchKernelGGL(prep_kernel, dim3(1), dim3(512), 0, stream,
                       W_ih, W_hh, b_ih, b_hh, whh_hi, whh_lo, wih, biasc);
    if (planes) {
        hipLaunchKernelGGL((lstm_kernel<true>), dim3(BATCH / 16), dim3(128), 0, stream,
                           x, whh_hi, whh_lo, wih, biasc, W_lin, data);
        hipLaunchKernelGGL(finalize_planes, dim3(BATCH / 4), dim3(256), 0, stream,
                           data, b_lin, out);
    } else {
        hipMemsetAsync(data, 0, 49160 * sizeof(float), stream);
        hipLaunchKernelGGL((lstm_kernel<false>), dim3(BATCH / 16), dim3(128), 0, stream,
                           x, whh_hi, whh_lo, wih, biasc, W_lin, data);
        hipLaunchKernelGGL(finalize_acc, dim3((BATCH * NOUT + 255) / 256), dim3(256), 0, stream,
                           data, b_lin, out);
    }
}